// Round 9
// baseline (38.302 us; speedup 1.0000x reference)
//
#include <hip/hip_runtime.h>
#include <math.h>

// UnrolledMeanShift: B=2, D=32, H=W=256, K=5x5, 3 iterations.
// R9 = R7's packed-fp16 named-SSA inner body with a 4-WAY channel split:
// 4 threads/pixel (8 ch = 1 LDS u4v word each) -> 524288 threads ->
// 32 waves/CU (2x R7) for latency hiding (R8 showed DS cut at lower
// occupancy LOSES; we are latency-bound, not DS-throughput-bound).
// Pixel's 4 lanes form a DPP quad; dist reduced with 2 quad_perm steps.
// NO per-thread arrays (R4-R6 lesson: aggregates go to scratch).

typedef _Float16 h2  __attribute__((ext_vector_type(2)));
typedef _Float16 h8  __attribute__((ext_vector_type(8)));
typedef unsigned int u4v __attribute__((ext_vector_type(4)));

constexpr int Dch  = 32;
constexpr int HH   = 256;
constexpr int WW   = 256;
constexpr int PADp = 2;
constexpr int BH   = 8;               // tile rows
constexpr int BW   = 16;              // tile cols
constexpr int TH   = BH + 2 * PADp;   // 12 halo rows
constexpr int TWd  = BW + 2 * PADp;   // 20 halo cols
constexpr int RSTR = 21;              // padded row stride (u4v words)
constexpr int PSTR = TH * RSTR + 1;   // 253 words plane stride (odd -> bank spread)
constexpr int ITERS = 3;
constexpr int HWp  = HH * WW;
constexpr int NTHR = 512;             // 128 pixels x 4 ch-quarter threads

__device__ __forceinline__ float fdot2f(h2 a, h2 b, float c) {
    return __builtin_amdgcn_fdot2(a, b, c, false);
}

__device__ __forceinline__ float EXP2F(float x) {
#if __has_builtin(__builtin_amdgcn_exp2f)
    return __builtin_amdgcn_exp2f(x);
#else
    return __expf(x * 0.69314718055994531f);
#endif
}

// lane^1 within quad (quad_perm [1,0,3,2])
__device__ __forceinline__ float qswap1(float x) {
    return __int_as_float(
        __builtin_amdgcn_mov_dpp(__float_as_int(x), 0xB1, 0xF, 0xF, true));
}
// lane^2 within quad (quad_perm [2,3,0,1])
__device__ __forceinline__ float qswap2(float x) {
    return __int_as_float(
        __builtin_amdgcn_mov_dpp(__float_as_int(x), 0x4E, 0xF, 0xF, true));
}

__device__ __forceinline__ h2 as_h2(unsigned int x) {
    return __builtin_bit_cast(h2, x);
}

__global__ __launch_bounds__(NTHR, 8)
void meanshift_kernel(const float* __restrict__ E,
                      const float* __restrict__ lbw,
                      float* __restrict__ out)
{
    __shared__ u4v tile[4 * PSTR];       // 4 planes x 253 words = 16.2 KB

    const int bz  = blockIdx.z;
    const int oh  = blockIdx.y * BH - PADp;
    const int ow  = blockIdx.x * BW - PADp;
    const int tid = threadIdx.x;
    const int cq  = tid & 3;             // channel quarter 0..3 (DPP quad!)
    const int idx = tid >> 2;            // 0..127 pixel in tile
    const int px  = idx & (BW - 1);      // 0..15
    const int py  = idx >> 4;            // 0..7

    const float bwv   = log1pf(__expf(lbw[0]));   // softplus
    const float cc2   = 1.0f / (2.0f * bwv * bwv);
    const float negNC = -cc2 * 1.44269504f;       // w = exp2(negNC * dist^2)

    const float* Eb = E + (size_t)bz * Dch * HWp;

    // ---- stage halo tile into LDS as fp16 ----
    for (int job = tid; job < 4 * (TH * TWd); job += NTHR) {
        const int cc = job / (TH * TWd);
        const int p  = job - cc * (TH * TWd);
        const int tr = p / TWd;
        const int tc = p - tr * TWd;
        const int gh = oh + tr;
        const int gw = ow + tc;
        h8 v;
        if ((unsigned)gh < (unsigned)HH && (unsigned)gw < (unsigned)WW) {
            const float* p0 = Eb + (size_t)(8 * cc) * HWp + gh * WW + gw;
            #pragma unroll
            for (int k = 0; k < 8; ++k) v[k] = (_Float16)p0[k * HWp];
        } else {
            #pragma unroll
            for (int k = 0; k < 8; ++k) v[k] = (_Float16)0.f;
        }
        tile[cc * PSTR + tr * RSTR + tc] = __builtin_bit_cast(u4v, v);
    }
    __syncthreads();

    const u4v* __restrict__ tP = tile + cq * PSTR;   // my 8-channel plane

    // ---- init z = own pixel, my 8 channels (named packed h2) ----
    h2 z0, z1, z2, z3;
    {
        const u4v ca = tP[(py + 2) * RSTR + (px + 2)];
        z0 = as_h2(ca[0]); z1 = as_h2(ca[1]);
        z2 = as_h2(ca[2]); z3 = as_h2(ca[3]);
    }

    float* Ob = out + (size_t)bz * Dch * HWp;
    const int off    = (oh + PADp + py) * WW + (ow + PADp + px);
    const int chbase = 8 * cq;

#define NBODY(Q) do {                                                         \
        const h2 p0 = as_h2(Q[0]), p1 = as_h2(Q[1]);                          \
        const h2 p2 = as_h2(Q[2]), p3 = as_h2(Q[3]);                          \
        const h2 e0 = p0 - z0, e1 = p1 - z1;                                  \
        const h2 e2 = p2 - z2, e3 = p3 - z3;                                  \
        float s0 = fdot2f(e0, e0, 0.f);                                       \
        float s1 = fdot2f(e1, e1, 0.f);                                       \
        s0 = fdot2f(e2, e2, s0);                                              \
        s1 = fdot2f(e3, e3, s1);                                              \
        const float dp = s0 + s1;             /* my 8 channels */             \
        const float d2 = dp + qswap1(dp);                                     \
        const float dist = d2 + qswap2(d2);   /* full 32 channels */          \
        const float w = EXP2F(dist * negNC);                                  \
        den += w;                                                             \
        const _Float16 wh = (_Float16)w;                                      \
        const h2 w2v = {wh, wh};                                              \
        n0 += p0 * w2v; n1 += p1 * w2v;                                       \
        n2 += p2 * w2v; n3 += p3 * w2v;                                       \
    } while (0)

    #pragma unroll 1
    for (int it = 0; it < ITERS; ++it) {
        h2 n0 = {(_Float16)0.f, (_Float16)0.f};
        h2 n1 = n0, n2 = n0, n3 = n0;
        float den = 0.f;

        #pragma unroll 1
        for (int di = 0; di < 5; ++di) {
            const int rwb = (py + di) * RSTR + px;
            const u4v q0 = tP[rwb + 0];
            const u4v q1 = tP[rwb + 1];
            const u4v q2 = tP[rwb + 2];
            const u4v q3 = tP[rwb + 3];
            const u4v q4 = tP[rwb + 4];
            NBODY(q0);
            NBODY(q1);
            NBODY(q2);
            NBODY(q3);
            NBODY(q4);
        }

        const float invf = 1.0f / (den + 1e-6f);
        if (it == ITERS - 1) {
#define WR(IDX, NV, EL) Ob[(size_t)(chbase + (IDX)) * HWp + off] = (float)NV[EL] * invf
            WR(0, n0, 0); WR(1, n0, 1); WR(2, n1, 0); WR(3, n1, 1);
            WR(4, n2, 0); WR(5, n2, 1); WR(6, n3, 0); WR(7, n3, 1);
#undef WR
        } else {
            const _Float16 ih = (_Float16)invf;
            const h2 iv = {ih, ih};
            z0 = n0 * iv; z1 = n1 * iv; z2 = n2 * iv; z3 = n3 * iv;
        }
    }
#undef NBODY
}

extern "C" void kernel_launch(void* const* d_in, const int* in_sizes, int n_in,
                              void* d_out, int out_size, void* d_ws, size_t ws_size,
                              hipStream_t stream) {
    const float* E   = (const float*)d_in[0];
    const float* lbw = (const float*)d_in[1];
    float* out       = (float*)d_out;

    const int B = in_sizes[0] / (Dch * HWp);       // = 2
    dim3 grid(WW / BW, HH / BH, B);                // (16,32,2) = 1024 blocks
    dim3 block(NTHR, 1, 1);                        // 512 threads (4/pixel)
    hipLaunchKernelGGL(meanshift_kernel, grid, block, 0, stream, E, lbw, out);
}